// Round 9
// baseline (1841.938 us; speedup 1.0000x reference)
//
#include <hip/hip_runtime.h>

// LSTM_77893526880768: B=T=F=H=256.  256 independent row-chains, 255 steps.
//
// v18 = v17 + o-gate weights in registers + predicated h reads (LDS ~0).
//
// Evidence ladder:
//   v9 4.78us/step | v12 5.24 | v14 4.42 | v15 2.85 (weights pinned) |
//   v16 2.35 | v17 2.34 (XCD swizzle: FETCH 525->68 MB, dur UNCHANGED ->
//   fetch was masked by L3 BW, not the limiter).
//   Clock FIXED ~750 MHz (5x independent MFMA-cycle checks).
//   v17 budget (1755cy/step): MFMA 620/SIMD (invariant) + VALU 414 + LDS
//   768/CU (24x ds_read_b128/wave: o_w re-read every step 512cy + h 256cy,
//   7/8 of h rows are structural zeros) + conflicts 272.
//
// v18 removes the LDS term:
//   - o_w -> oreg[2][8] registers (64 regs), pinned by the v15 clobber.
//     LDS o-traffic 512cy -> 0.  128KB LDS block gone.
//   - h A-frag read predicated: only cl<2 lanes load (rows 2..15 are zero
//     -> zero regs, MFMA C rows 2..15 were zero anyway).  h LDS 8x down;
//     surviving 8 lanes are 2-way bank-aliased (free, m136).
//   - hbuf shrunk to rows 0..1: [2][512] ushort = 2 KB total LDS.
//   Everything else (XCD swizzle, EW redistribution, P access) = v17.
//
// Workspace layout:
//   [0, 512K)       WxT bf16   (dead after precompute)
//   [512K, 1M)      WhT bf16
//   [1M, 1M+4K)     bcat fp32
//   [1M+4K, ...)    P bf16  [t][rg16][n][16] = 133,693,440 B

#define STEPS 255

typedef short bf16x8 __attribute__((ext_vector_type(8)));
typedef short bf16x4 __attribute__((ext_vector_type(4)));
typedef float f32x4  __attribute__((ext_vector_type(4)));

__device__ inline unsigned short f2bf(float f) {
  unsigned int u = __float_as_uint(f);
  unsigned int r = (u + 0x7FFFu + ((u >> 16) & 1u)) >> 16;  // RNE
  return (unsigned short)r;
}
__device__ inline float bf2f(unsigned short s) {
  return __uint_as_float(((unsigned int)s) << 16);
}
__device__ inline float sig_f(float x) {
  float e = exp2f(-1.442695041f * x);
  return __builtin_amdgcn_rcpf(1.0f + e);
}
__device__ inline float tanh_f(float x) {
  float e = exp2f(-2.885390082f * x);
  return 2.0f * __builtin_amdgcn_rcpf(1.0f + e) - 1.0f;
}

// ---------- prep: W transpose (W[k][j] fp32 -> WT[g*256+j][k] bf16) ----------
__global__ __launch_bounds__(256) void lstm_prep_w(
    const float* __restrict__ m0, const float* __restrict__ m1,
    const float* __restrict__ m2, const float* __restrict__ m3,
    const float* __restrict__ m4, const float* __restrict__ m5,
    const float* __restrict__ m6, const float* __restrict__ m7,
    unsigned short* __restrict__ WxT, unsigned short* __restrict__ WhT) {
  const float* mats[8] = {m0, m1, m2, m3, m4, m5, m6, m7};
  int mat = blockIdx.z;
  const float* W = mats[mat];
  unsigned short* out = (mat < 4 ? WxT : WhT) + (size_t)(mat & 3) * 256 * 256;
  int kblk = blockIdx.x * 32, jblk = blockIdx.y * 32;
  __shared__ float tile[32][33];
  int tx = threadIdx.x & 31, ty = threadIdx.x >> 5;
#pragma unroll
  for (int i = 0; i < 4; ++i) {
    int kk = ty + i * 8;
    tile[kk][tx] = W[(size_t)(kblk + kk) * 256 + jblk + tx];
  }
  __syncthreads();
#pragma unroll
  for (int i = 0; i < 4; ++i) {
    int jj = ty + i * 8;
    out[(size_t)(jblk + jj) * 256 + kblk + tx] = f2bf(tile[tx][jj]);
  }
}

// ---------- prep: bias fold ----------
__global__ void lstm_prep_b(
    const float* __restrict__ bx0, const float* __restrict__ bx1,
    const float* __restrict__ bx2, const float* __restrict__ bx3,
    const float* __restrict__ bh0, const float* __restrict__ bh1,
    const float* __restrict__ bh2, const float* __restrict__ bh3,
    float* __restrict__ bcat) {
  const float* bx[4] = {bx0, bx1, bx2, bx3};
  const float* bh[4] = {bh0, bh1, bh2, bh3};
  int i = blockIdx.x * 256 + threadIdx.x;
  int g = i >> 8, j = i & 255;
  bcat[i] = bx[g][j] + bh[g][j];
}

// ---------- precompute: P[t][rg16][n][rl] = bcat[n] + sum_k x[r,t,k] Wx[k,n] ----------
// grid (255, 2): blockIdx.y selects 8 of the 16 n-blocks (x-frags duplicated).
__global__ __launch_bounds__(256, 1) void lstm_precompute(
    const float* __restrict__ x, const unsigned short* __restrict__ WxT,
    const float* __restrict__ bcat, unsigned short* __restrict__ P) {
  int t = blockIdx.x;
  int tid = threadIdx.x;
  int w = tid >> 6, lane = tid & 63, q = lane >> 4, cl = lane & 15;
  int rbase = w * 64;

  bf16x8 bfrag[8][4];
#pragma unroll
  for (int kt = 0; kt < 8; ++kt) {
    int k0 = kt * 32 + q * 8;
#pragma unroll
    for (int rt = 0; rt < 4; ++rt) {
      const float* xp = x + (((size_t)(rbase + rt * 16 + cl) * 256 + t) * 256 + k0);
      f32x4 lo = *(const f32x4*)xp;
      f32x4 hi = *(const f32x4*)(xp + 4);
      bf16x8 bv;
      bv[0] = (short)f2bf(lo[0]); bv[1] = (short)f2bf(lo[1]);
      bv[2] = (short)f2bf(lo[2]); bv[3] = (short)f2bf(lo[3]);
      bv[4] = (short)f2bf(hi[0]); bv[5] = (short)f2bf(hi[1]);
      bv[6] = (short)f2bf(hi[2]); bv[7] = (short)f2bf(hi[3]);
      bfrag[kt][rt] = bv;
    }
  }

  for (int nbi = 0; nbi < 8; ++nbi) {
    int nblk = (blockIdx.y * 8 + nbi) * 64;
    f32x4 acc[4][4];
#pragma unroll
    for (int a = 0; a < 4; ++a)
#pragma unroll
      for (int b = 0; b < 4; ++b) acc[a][b] = f32x4{0.f, 0.f, 0.f, 0.f};

#pragma unroll
    for (int kt = 0; kt < 8; ++kt) {
      int k0 = kt * 32 + q * 8;
      bf16x8 afrag[4];
#pragma unroll
      for (int mt = 0; mt < 4; ++mt)
        afrag[mt] = *(const bf16x8*)(WxT + (size_t)(nblk + mt * 16 + cl) * 256 + k0);
#pragma unroll
      for (int mt = 0; mt < 4; ++mt)
#pragma unroll
        for (int rt = 0; rt < 4; ++rt)
          acc[mt][rt] = __builtin_amdgcn_mfma_f32_16x16x32_bf16(
              afrag[mt], bfrag[kt][rt], acc[mt][rt], 0, 0, 0);
    }
#pragma unroll
    for (int mt = 0; mt < 4; ++mt) {
#pragma unroll
      for (int reg = 0; reg < 4; ++reg) {
        int n = nblk + mt * 16 + q * 4 + reg;
        float bb = bcat[n];
#pragma unroll
        for (int rt = 0; rt < 4; ++rt) {
          int rg16 = w * 4 + rt;  // = r>>4
          P[(((size_t)t * 16 + rg16) * 1024 + n) * 16 + cl] = f2bf(acc[mt][rt][reg] + bb);
        }
      }
    }
  }
}

// ---------- recurrent v18: all weights in regs, 2KB LDS, predicated h reads ----------
__global__ __launch_bounds__(512, 2) void lstm_recurrent(
    const unsigned short* __restrict__ WhT,
    const unsigned short* __restrict__ P,
    float* __restrict__ out) {
  // h double buffer, rows 0..1 only, XOR-swizzled: byte ^= (row<<4).  2 KB.
  __shared__ unsigned short hbuf[2][512];

  int tid = threadIdx.x;
  int w = tid >> 6, lane = tid & 63, q = lane >> 4, cl = lane & 15;
  // XCD swizzle (v17-proven): the 8 WGs sharing P lines (same x>>3) get
  // identical b%8 -> one XCD -> each P line fetched into exactly one L2.
  int b_ = blockIdx.x;
  int x = (b_ & 7) * 16 + (b_ >> 3);  // bijective 0..127
  int rg16 = x >> 3;            // P row-group (global row >> 4)
  int idxb = (x & 7) * 2;       // P idx15 base for this WG's rows

  // ---- ALL weight tiles into registers (static indexing only -- rule #20)
  bf16x8 wreg[2][3][8];  // i,f,g: [block][gate][kt] = 48 frags
  bf16x8 oreg[2][8];     // o:     [block][kt]       = 16 frags
#pragma unroll
  for (int b = 0; b < 2; ++b) {
    int col = (2 * w + b) * 16 + cl;
#pragma unroll
    for (int g = 0; g < 3; ++g)
#pragma unroll
      for (int kt = 0; kt < 8; ++kt)
        wreg[b][g][kt] =
            *(const bf16x8*)(WhT + (size_t)(g * 256 + col) * 256 + kt * 32 + q * 8);
#pragma unroll
    for (int kt = 0; kt < 8; ++kt)
      oreg[b][kt] =
          *(const bf16x8*)(WhT + (size_t)(3 * 256 + col) * 256 + kt * 32 + q * 8);
  }

  // ---- zero BOTH h buffers (rows 0..1; h_0 = 0)
  for (int i = tid; i < 512; i += 512) ((unsigned int*)&hbuf[0][0])[i] = 0;

  // Memory clobber (v15-proven): rematerializing the weight global loads
  // across this fence is illegal => weight values stay register-resident.
  asm volatile("" ::: "memory");
  __syncthreads();

  // A-read base for the 2 valid rows (row = cl in {0,1}): byte =
  // cl*512 + (q*16 ^ (cl<<4)); per kt add XOR kt*64 (bit-disjoint).
  int abase = cl * 512 + ((q * 16) ^ ((cl & 7) << 4));
  bool ard = (cl < 2);  // only these lanes read h; rows 2..15 are zero

  // EW ownership: lane (q,cl) owns the single cell
  //   block bq = q>>1, local row rq = q&1, col = 32w + bq*16 + cl.
  int bq = q >> 1, rq = q & 1;
  int colq = 32 * w + bq * 16 + cl;
  int idx15 = idxb + rq;

  float creg = 0.f;

  for (int t = 0; t < STEPS; ++t) {
    int rb = t & 1;
    bool lastt = (t == STEPS - 1);
    const unsigned short* hr = &hbuf[rb][0];
    unsigned short* hw = &hbuf[rb ^ 1][0];

    // P loads for this lane's cell: issued at step start, consumed after
    // the MFMA phase -> L2/HBM latency stays hidden.
    unsigned short pv[4];
    {
      const unsigned short* pp =
          P + (((size_t)t * 16 + rg16) * 1024 + colq) * 16 + idx15;
#pragma unroll
      for (int g = 0; g < 4; ++g) pv[g] = pp[(size_t)g * 4096];
    }

    // ---- h A-fragments: predicated (rows 2..15 structurally zero)
    bf16x8 af[8];
#pragma unroll
    for (int kt = 0; kt < 8; ++kt) {
      bf16x8 z = {0, 0, 0, 0, 0, 0, 0, 0};
      if (ard) z = *(const bf16x8*)(hr + ((abase ^ (kt * 64)) >> 1));
      af[kt] = z;
    }

    // ---- MFMA: af feeds both blocks x 4 gates
    f32x4 acc[2][4];
#pragma unroll
    for (int b = 0; b < 2; ++b)
#pragma unroll
      for (int g = 0; g < 4; ++g) acc[b][g] = f32x4{0.f, 0.f, 0.f, 0.f};

#pragma unroll
    for (int kt = 0; kt < 8; ++kt) {
      acc[0][0] = __builtin_amdgcn_mfma_f32_16x16x32_bf16(af[kt], wreg[0][0][kt], acc[0][0], 0, 0, 0);
      acc[0][1] = __builtin_amdgcn_mfma_f32_16x16x32_bf16(af[kt], wreg[0][1][kt], acc[0][1], 0, 0, 0);
      acc[0][2] = __builtin_amdgcn_mfma_f32_16x16x32_bf16(af[kt], wreg[0][2][kt], acc[0][2], 0, 0, 0);
      acc[0][3] = __builtin_amdgcn_mfma_f32_16x16x32_bf16(af[kt], oreg[0][kt],    acc[0][3], 0, 0, 0);
      acc[1][0] = __builtin_amdgcn_mfma_f32_16x16x32_bf16(af[kt], wreg[1][0][kt], acc[1][0], 0, 0, 0);
      acc[1][1] = __builtin_amdgcn_mfma_f32_16x16x32_bf16(af[kt], wreg[1][1][kt], acc[1][1], 0, 0, 0);
      acc[1][2] = __builtin_amdgcn_mfma_f32_16x16x32_bf16(af[kt], wreg[1][2][kt], acc[1][2], 0, 0, 0);
      acc[1][3] = __builtin_amdgcn_mfma_f32_16x16x32_bf16(af[kt], oreg[1][kt],    acc[1][3], 0, 0, 0);
    }

    // ---- redistribute: valid C rows {0,1} sit at q=0, e={0,1} (per block).
    // Target: lane (q,cl) gets (block q>>1, row q&1).
    float sh1[4], sh2[4], sh3[4], ag[4];
#pragma unroll
    for (int g = 0; g < 4; ++g) {
      sh1[g] = __shfl_xor(acc[0][g][1], 16, 64);  // q=1 <- q=0: b0 row1
      sh2[g] = __shfl_xor(acc[1][g][0], 32, 64);  // q=2 <- q=0: b1 row0
      sh3[g] = __shfl_xor(acc[1][g][1], 48, 64);  // q=3 <- q=0: b1 row1
    }
#pragma unroll
    for (int g = 0; g < 4; ++g)
      ag[g] = (q == 0) ? acc[0][g][0]
            : (q == 1) ? sh1[g]
            : (q == 2) ? sh2[g]
                       : sh3[g];

    // ---- EW: exactly one LSTM cell per lane.
    {
      float pi = ag[0] + bf2f(pv[0]);
      float pf = ag[1] + bf2f(pv[1]);
      float pg = ag[2] + bf2f(pv[2]);
      float po = ag[3] + bf2f(pv[3]);
      float ig = sig_f(pi), fg = sig_f(pf), gg = tanh_f(pg), og = sig_f(po);
      float cn = fg * creg + ig * gg;
      creg = cn;
      float hn = og * tanh_f(cn);
      if (!lastt) {
        int wb = rq * 512 + ((colq * 2) ^ (rq << 4));
        hw[wb >> 1] = f2bf(hn);
      } else {
        out[(size_t)(x * 2 + rq) * 256 + colq] = hn;
        out[65536 + (size_t)(x * 2 + rq) * 256 + colq] = cn;
      }
    }

    __syncthreads();  // h(t+1) complete before step t+1 reads it
  }
}

extern "C" void kernel_launch(void* const* d_in, const int* in_sizes, int n_in,
                              void* d_out, int out_size, void* d_ws, size_t ws_size,
                              hipStream_t stream) {
  const float* x = (const float*)d_in[0];
  const float* wx0 = (const float*)d_in[1];
  const float* wx1 = (const float*)d_in[5];
  const float* wx2 = (const float*)d_in[9];
  const float* wx3 = (const float*)d_in[13];
  const float* wh0 = (const float*)d_in[3];
  const float* wh1 = (const float*)d_in[7];
  const float* wh2 = (const float*)d_in[11];
  const float* wh3 = (const float*)d_in[15];
  const float* bx0 = (const float*)d_in[2];
  const float* bx1 = (const float*)d_in[6];
  const float* bx2 = (const float*)d_in[10];
  const float* bx3 = (const float*)d_in[14];
  const float* bh0 = (const float*)d_in[4];
  const float* bh1 = (const float*)d_in[8];
  const float* bh2 = (const float*)d_in[12];
  const float* bh3 = (const float*)d_in[16];

  char* ws = (char*)d_ws;
  unsigned short* WxT = (unsigned short*)(ws + 0);          // dead after precompute
  unsigned short* WhT = (unsigned short*)(ws + 524288);
  float* bcat = (float*)(ws + 1048576);
  unsigned short* P = (unsigned short*)(ws + 1052672);      // [t][rg16][n][16] bf16

  lstm_prep_w<<<dim3(8, 8, 8), 256, 0, stream>>>(wx0, wx1, wx2, wx3,
                                                 wh0, wh1, wh2, wh3, WxT, WhT);
  lstm_prep_b<<<4, 256, 0, stream>>>(bx0, bx1, bx2, bx3, bh0, bh1, bh2, bh3, bcat);
  lstm_precompute<<<dim3(255, 2), 256, 0, stream>>>(x, WxT, bcat, P);
  lstm_recurrent<<<dim3(128), 512, 0, stream>>>(WhT, P, (float*)d_out);
}